// Round 1
// baseline (500.721 us; speedup 1.0000x reference)
//
#include <hip/hip_runtime.h>
#include <hip/hip_bf16.h>

typedef __attribute__((ext_vector_type(8))) short s8v;
typedef __attribute__((ext_vector_type(4))) short s4v;
typedef __attribute__((ext_vector_type(4))) float f4v;

#define DIM 2048
#define NROW 512   // 2*B
#define NB 256     // B

__device__ inline short f2bf(float f) {
    union { float f; unsigned int u; } v; v.f = f;
    unsigned int u = v.u;
    unsigned int r = (u + 0x7fffu + ((u >> 16) & 1u)) >> 16;
    return (short)r;
}

// ---- 1. spatial mean pool: z0/z1 (256,2048,8,8) fp32 -> p (512,2048) bf16 ----
__global__ __launch_bounds__(256) void pool_kernel(const float* __restrict__ z0,
                                                   const float* __restrict__ z1,
                                                   short* __restrict__ p) {
    int t = threadIdx.x;
    int pb = blockIdx.x * 64;
    for (int pass = 0; pass < 4; ++pass) {
        int pair = pb + pass * 16 + (t >> 4);   // pair = r*2048 + d
        int fidx = t & 15;
        long off = (long)pair * 64 + fidx * 4;
        const float* src = (pair < NB * DIM) ? (z0 + off)
                                             : (z1 + (off - (long)NB * DIM * 64));
        float4 v = *(const float4*)src;
        float s = v.x + v.y + v.z + v.w;
        s += __shfl_xor(s, 1);
        s += __shfl_xor(s, 2);
        s += __shfl_xor(s, 4);
        s += __shfl_xor(s, 8);
        if (fidx == 0) p[pair] = f2bf(s * (1.0f / 64.0f));
    }
}

// ---- 2. fp32 -> bf16 cast (for W1/W2) ----
__global__ __launch_bounds__(256) void cast_kernel(const float* __restrict__ in,
                                                   short* __restrict__ out) {
    int idx = (blockIdx.x * 256 + threadIdx.x) * 4;
    float4 v = *(const float4*)(in + idx);
    s4v o;
    o.x = f2bf(v.x); o.y = f2bf(v.y); o.z = f2bf(v.z); o.w = f2bf(v.w);
    *(s4v*)(out + idx) = o;
}

// ---- 3. bf16 NT GEMM: C[m][n] = sum_k A[m][k]*B[n][k] + bias[n] ----
// 128x128 tile per block (256 thr = 4 waves, each wave 64x64), BK=64.
__global__ __launch_bounds__(256) void gemm_bt(const short* __restrict__ A,
                                               const short* __restrict__ Bm,
                                               const float* __restrict__ bias,
                                               float* __restrict__ C,
                                               int M, int N, int K) {
    __shared__ short lA[128 * 72];
    __shared__ short lB[128 * 72];
    int t = threadIdx.x;
    int n0 = blockIdx.x * 128, m0 = blockIdx.y * 128;
    int lane = t & 63, wave = t >> 6;
    int wm = wave & 1, wn = wave >> 1;
    int l16 = lane & 15, quad = lane >> 4;
    f4v acc[4][4] = {};

    int srow = t >> 3;          // 0..31
    int scol = (t & 7) * 8;     // 0..56 step 8

    for (int k0 = 0; k0 < K; k0 += 64) {
#pragma unroll
        for (int i = 0; i < 4; ++i) {
            int r = srow + 32 * i;
            *(s8v*)&lA[r * 72 + scol] = *(const s8v*)&A[(long)(m0 + r) * K + k0 + scol];
            *(s8v*)&lB[r * 72 + scol] = *(const s8v*)&Bm[(long)(n0 + r) * K + k0 + scol];
        }
        __syncthreads();
#pragma unroll
        for (int kk = 0; kk < 2; ++kk) {
            s8v af[4], bf[4];
#pragma unroll
            for (int i = 0; i < 4; ++i)
                af[i] = *(const s8v*)&lA[(wm * 64 + i * 16 + l16) * 72 + kk * 32 + quad * 8];
#pragma unroll
            for (int i = 0; i < 4; ++i)
                bf[i] = *(const s8v*)&lB[(wn * 64 + i * 16 + l16) * 72 + kk * 32 + quad * 8];
#pragma unroll
            for (int i = 0; i < 4; ++i)
#pragma unroll
                for (int j = 0; j < 4; ++j)
                    acc[i][j] = __builtin_amdgcn_mfma_f32_16x16x32_bf16(af[i], bf[j], acc[i][j], 0, 0, 0);
        }
        __syncthreads();
    }

#pragma unroll
    for (int i = 0; i < 4; ++i) {
        int rowg = m0 + wm * 64 + i * 16 + quad * 4;
#pragma unroll
        for (int j = 0; j < 4; ++j) {
            int colg = n0 + wn * 64 + j * 16 + l16;
            float bv = bias ? bias[colg] : 0.0f;
#pragma unroll
            for (int r = 0; r < 4; ++r)
                C[(long)(rowg + r) * N + colg] = acc[i][j][r] + bv;
        }
    }
}

// ---- 4. batchnorm stats over 512 rows per column -> scale/shift ----
__global__ __launch_bounds__(256) void bn_stats(const float* __restrict__ h,
                                                const float* __restrict__ gamma,
                                                const float* __restrict__ beta,
                                                float* __restrict__ scale,
                                                float* __restrict__ shift) {
    __shared__ float ssum[4][64], ssq[4][64];
    int t = threadIdx.x;
    int col = blockIdx.x * 64 + (t & 63);
    int part = t >> 6;
    float sum = 0.f, sq = 0.f;
    for (int r = part; r < NROW; r += 4) {
        float v = h[(long)r * DIM + col];
        sum += v; sq += v * v;
    }
    ssum[part][t & 63] = sum; ssq[part][t & 63] = sq;
    __syncthreads();
    if (t < 64) {
        float s = ssum[0][t] + ssum[1][t] + ssum[2][t] + ssum[3][t];
        float q = ssq[0][t] + ssq[1][t] + ssq[2][t] + ssq[3][t];
        float mu = s * (1.0f / NROW);
        float var = q * (1.0f / NROW) - mu * mu;
        int c = blockIdx.x * 64 + t;
        float sc = gamma[c] * rsqrtf(var + 1e-5f);
        scale[c] = sc;
        shift[c] = beta[c] - mu * sc;
    }
}

// ---- 5. bn apply + relu + cast bf16 ----
__global__ __launch_bounds__(256) void bn_relu_cast(const float* __restrict__ h,
                                                    const float* __restrict__ scale,
                                                    const float* __restrict__ shift,
                                                    short* __restrict__ hn) {
    int idx = (blockIdx.x * 256 + threadIdx.x) * 4;
    int col = idx & (DIM - 1);
    float4 v = *(const float4*)(h + idx);
    float4 sc = *(const float4*)(scale + col);
    float4 sh = *(const float4*)(shift + col);
    s4v o;
    o.x = f2bf(fmaxf(v.x * sc.x + sh.x, 0.f));
    o.y = f2bf(fmaxf(v.y * sc.y + sh.y, 0.f));
    o.z = f2bf(fmaxf(v.z * sc.z + sh.z, 0.f));
    o.w = f2bf(fmaxf(v.w * sc.w + sh.w, 0.f));
    *(s4v*)(hn + idx) = o;
}

// ---- 6. row L2 normalize + cast bf16 ----
__global__ __launch_bounds__(256) void rownorm(const float* __restrict__ z,
                                               short* __restrict__ zn) {
    __shared__ float red[4];
    int row = blockIdx.x, t = threadIdx.x;
    const float* zr = z + (long)row * DIM;
    float4 v0 = *(const float4*)(zr + t * 4);
    float4 v1 = *(const float4*)(zr + 1024 + t * 4);
    float ss = v0.x * v0.x + v0.y * v0.y + v0.z * v0.z + v0.w * v0.w
             + v1.x * v1.x + v1.y * v1.y + v1.z * v1.z + v1.w * v1.w;
#pragma unroll
    for (int m = 1; m < 64; m <<= 1) ss += __shfl_xor(ss, m);
    if ((t & 63) == 0) red[t >> 6] = ss;
    __syncthreads();
    float tot = red[0] + red[1] + red[2] + red[3];
    float inv = 1.0f / fmaxf(sqrtf(tot), 1e-8f);
    s4v a, b;
    a.x = f2bf(v0.x * inv); a.y = f2bf(v0.y * inv); a.z = f2bf(v0.z * inv); a.w = f2bf(v0.w * inv);
    b.x = f2bf(v1.x * inv); b.y = f2bf(v1.y * inv); b.z = f2bf(v1.z * inv); b.w = f2bf(v1.w * inv);
    *(s4v*)(zn + (long)row * DIM + t * 4) = a;
    *(s4v*)(zn + (long)row * DIM + 1024 + t * 4) = b;
}

// ---- 7. loss: sim(256x512) + rel -> (loss, n_defined). single block. ----
__global__ __launch_bounds__(1024) void loss_kernel(const float* __restrict__ sim,
                                                    const int* __restrict__ rel,
                                                    float* __restrict__ out) {
    __shared__ float lsum[16];
    __shared__ int lcnt[16];
    int t = threadIdx.x, lane = t & 63, wave = t >> 6;
    float loss = 0.f; int ndef = 0;
    for (int i = wave; i < NB; i += 16) {
        int reli = rel[i];
        float s[8], e[8];
        float neg = 0.f;
#pragma unroll
        for (int kk = 0; kk < 8; ++kk) {
            int j = lane + kk * 64;
            s[kk] = sim[i * 512 + j];
            e[kk] = __expf(10.0f * s[kk]);
            if (j >= NB) neg += e[kk];
            else if (abs(reli - rel[j]) > 2) neg += e[kk];
        }
#pragma unroll
        for (int m = 1; m < 64; m <<= 1) neg += __shfl_xor(neg, m);
        float ts = 0.f; int cnt = 0;
#pragma unroll
        for (int kk = 0; kk < 4; ++kk) {
            int j = lane + kk * 64;
            if (j != i && abs(reli - rel[j]) <= 2) {
                ts += logf(e[kk] + neg) - 10.0f * s[kk];
                cnt++;
            }
        }
#pragma unroll
        for (int m = 1; m < 64; m <<= 1) {
            ts += __shfl_xor(ts, m);
            cnt += __shfl_xor(cnt, m);
        }
        if (cnt > 0) { loss += ts / (float)cnt; ndef++; }
    }
    if (lane == 0) { lsum[wave] = loss; lcnt[wave] = ndef; }
    __syncthreads();
    if (t == 0) {
        float L = 0.f; int n = 0;
        for (int w = 0; w < 16; ++w) { L += lsum[w]; n += lcnt[w]; }
        out[0] = L;
        out[1] = (float)n;
    }
}

extern "C" void kernel_launch(void* const* d_in, const int* in_sizes, int n_in,
                              void* d_out, int out_size, void* d_ws, size_t ws_size,
                              hipStream_t stream) {
    const float* z0    = (const float*)d_in[0];
    const float* z1    = (const float*)d_in[1];
    const int*   rel0  = (const int*)d_in[2];
    // d_in[3] = rel_slice_idx_1 : unused by reference
    const float* W1    = (const float*)d_in[4];
    const float* b1    = (const float*)d_in[5];
    const float* gamma = (const float*)d_in[6];
    const float* beta  = (const float*)d_in[7];
    const float* W2    = (const float*)d_in[8];
    const float* b2    = (const float*)d_in[9];

    char* ws = (char*)d_ws;
    short* p_bf  = (short*)(ws);                         // 512*2048*2  = 2 MB
    short* W1b   = (short*)(ws + (2l  << 20));           // 8 MB
    short* W2b   = (short*)(ws + (10l << 20));           // 8 MB
    float* h     = (float*)(ws + (18l << 20));           // 4 MB
    float* scale = (float*)(ws + (22l << 20));           // 8 KB
    float* shift = (float*)(ws + (22l << 20) + 16384);   // 8 KB
    short* hn    = (short*)(ws + (23l << 20));           // 2 MB
    float* zproj = (float*)(ws + (25l << 20));           // 4 MB
    short* zn    = (short*)(ws + (29l << 20));           // 2 MB
    float* sim   = (float*)(ws + (31l << 20));           // 512 KB

    pool_kernel<<<16384, 256, 0, stream>>>(z0, z1, p_bf);
    cast_kernel<<<4096, 256, 0, stream>>>(W1, W1b);
    cast_kernel<<<4096, 256, 0, stream>>>(W2, W2b);
    gemm_bt<<<dim3(16, 4), 256, 0, stream>>>(p_bf, W1b, b1, h, NROW, DIM, DIM);
    bn_stats<<<32, 256, 0, stream>>>(h, gamma, beta, scale, shift);
    bn_relu_cast<<<1024, 256, 0, stream>>>(h, scale, shift, hn);
    gemm_bt<<<dim3(16, 4), 256, 0, stream>>>(hn, W2b, b2, zproj, NROW, DIM, DIM);
    rownorm<<<512, 256, 0, stream>>>(zproj, zn);
    gemm_bt<<<dim3(4, 2), 256, 0, stream>>>(zn, zn, nullptr, sim, NB, NROW, DIM);
    loss_kernel<<<1, 1024, 0, stream>>>(sim, rel0, (float*)d_out);
}

// Round 2
// 474.364 us; speedup vs baseline: 1.0556x; 1.0556x over previous
//
#include <hip/hip_runtime.h>
#include <hip/hip_bf16.h>

typedef __attribute__((ext_vector_type(8))) short s8v;
typedef __attribute__((ext_vector_type(4))) short s4v;
typedef __attribute__((ext_vector_type(4))) float f4v;

#define DIM 2048
#define NROW 512   // 2*B
#define NB 256     // B

__device__ inline short f2bf(float f) {
    union { float f; unsigned int u; } v; v.f = f;
    unsigned int u = v.u;
    unsigned int r = (u + 0x7fffu + ((u >> 16) & 1u)) >> 16;
    return (short)r;
}

// ---- 1. spatial mean pool: z0/z1 (256,2048,8,8) fp32 -> p (512,2048) bf16 ----
// Each block owns a contiguous 32 KB input region (128 pairs). 8 independent
// float4 loads per thread issued before any reduction (ILP for latency hiding).
__global__ __launch_bounds__(256) void pool_kernel(const float* __restrict__ z0,
                                                   const float* __restrict__ z1,
                                                   short* __restrict__ p) {
    int t = threadIdx.x;
    int b = blockIdx.x;
    const float* src = (b < 4096) ? (z0 + (long)b * 8192)
                                  : (z1 + (long)(b - 4096) * 8192);
    float4 v[8];
#pragma unroll
    for (int i = 0; i < 8; ++i)
        v[i] = *(const float4*)(src + i * 1024 + t * 4);
    int pairBase = b * 128;
#pragma unroll
    for (int i = 0; i < 8; ++i) {
        float s = v[i].x + v[i].y + v[i].z + v[i].w;
        s += __shfl_xor(s, 1);
        s += __shfl_xor(s, 2);
        s += __shfl_xor(s, 4);
        s += __shfl_xor(s, 8);
        if ((t & 15) == 0)
            p[pairBase + i * 16 + (t >> 4)] = f2bf(s * (1.0f / 64.0f));
    }
}

// ---- 2. fp32 -> bf16 cast for W1 and W2 in one launch ----
__global__ __launch_bounds__(256) void cast2_kernel(const float* __restrict__ a,
                                                    const float* __restrict__ b,
                                                    short* __restrict__ oa,
                                                    short* __restrict__ ob) {
    int bid = blockIdx.x;
    const float* in = (bid < 4096) ? a : b;
    short* out = (bid < 4096) ? oa : ob;
    int idx = ((bid & 4095) * 256 + threadIdx.x) * 4;
    float4 v = *(const float4*)(in + idx);
    s4v o;
    o.x = f2bf(v.x); o.y = f2bf(v.y); o.z = f2bf(v.z); o.w = f2bf(v.w);
    *(s4v*)(out + idx) = o;
}

// ---- 3. bf16 NT GEMM, 64x64 tile / block, optional split-K via blockIdx.z ----
// C[z*M*N + m*N + n] = sum_{k in chunk z} A[m][k]*B[n][k] + bias[n]
__global__ __launch_bounds__(256) void gemm64(const short* __restrict__ A,
                                              const short* __restrict__ Bm,
                                              const float* __restrict__ bias,
                                              float* __restrict__ C,
                                              int M, int N, int K, int kChunk) {
    __shared__ short lA[64 * 72];
    __shared__ short lB[64 * 72];
    int t = threadIdx.x;
    int n0 = blockIdx.x * 64, m0 = blockIdx.y * 64;
    int kBegin = blockIdx.z * kChunk, kEnd = kBegin + kChunk;
    long zoff = (long)blockIdx.z * M * N;
    int lane = t & 63, wave = t >> 6;
    int wm = wave & 1, wn = wave >> 1;
    int l16 = lane & 15, quad = lane >> 4;
    f4v acc[2][2] = {};
    int srow = t >> 3;          // 0..31
    int scol = (t & 7) * 8;     // 0..56 step 8

    for (int k0 = kBegin; k0 < kEnd; k0 += 64) {
#pragma unroll
        for (int i = 0; i < 2; ++i) {
            int r = srow + 32 * i;
            *(s8v*)&lA[r * 72 + scol] = *(const s8v*)&A[(long)(m0 + r) * K + k0 + scol];
            *(s8v*)&lB[r * 72 + scol] = *(const s8v*)&Bm[(long)(n0 + r) * K + k0 + scol];
        }
        __syncthreads();
#pragma unroll
        for (int kk = 0; kk < 2; ++kk) {
            s8v af[2], bf[2];
#pragma unroll
            for (int i = 0; i < 2; ++i)
                af[i] = *(const s8v*)&lA[(wm * 32 + i * 16 + l16) * 72 + kk * 32 + quad * 8];
#pragma unroll
            for (int i = 0; i < 2; ++i)
                bf[i] = *(const s8v*)&lB[(wn * 32 + i * 16 + l16) * 72 + kk * 32 + quad * 8];
#pragma unroll
            for (int i = 0; i < 2; ++i)
#pragma unroll
                for (int j = 0; j < 2; ++j)
                    acc[i][j] = __builtin_amdgcn_mfma_f32_16x16x32_bf16(af[i], bf[j], acc[i][j], 0, 0, 0);
        }
        __syncthreads();
    }

#pragma unroll
    for (int i = 0; i < 2; ++i) {
        int rowg = m0 + wm * 32 + i * 16 + quad * 4;
#pragma unroll
        for (int j = 0; j < 2; ++j) {
            int colg = n0 + wn * 32 + j * 16 + l16;
            float bv = bias ? bias[colg] : 0.0f;
#pragma unroll
            for (int r = 0; r < 4; ++r)
                C[zoff + (long)(rowg + r) * N + colg] = acc[i][j][r] + bv;
        }
    }
}

// ---- 4. batchnorm stats over 512 rows per column -> scale/shift ----
__global__ __launch_bounds__(256) void bn_stats(const float* __restrict__ h,
                                                const float* __restrict__ gamma,
                                                const float* __restrict__ beta,
                                                float* __restrict__ scale,
                                                float* __restrict__ shift) {
    __shared__ float ssum[4][64], ssq[4][64];
    int t = threadIdx.x;
    int col = blockIdx.x * 64 + (t & 63);
    int part = t >> 6;
    float sum = 0.f, sq = 0.f;
    for (int r = part; r < NROW; r += 4) {
        float v = h[(long)r * DIM + col];
        sum += v; sq += v * v;
    }
    ssum[part][t & 63] = sum; ssq[part][t & 63] = sq;
    __syncthreads();
    if (t < 64) {
        float s = ssum[0][t] + ssum[1][t] + ssum[2][t] + ssum[3][t];
        float q = ssq[0][t] + ssq[1][t] + ssq[2][t] + ssq[3][t];
        float mu = s * (1.0f / NROW);
        float var = q * (1.0f / NROW) - mu * mu;
        int c = blockIdx.x * 64 + t;
        float sc = gamma[c] * rsqrtf(var + 1e-5f);
        scale[c] = sc;
        shift[c] = beta[c] - mu * sc;
    }
}

// ---- 5. bn apply + relu + cast bf16 ----
__global__ __launch_bounds__(256) void bn_relu_cast(const float* __restrict__ h,
                                                    const float* __restrict__ scale,
                                                    const float* __restrict__ shift,
                                                    short* __restrict__ hn) {
    int idx = (blockIdx.x * 256 + threadIdx.x) * 4;
    int col = idx & (DIM - 1);
    float4 v = *(const float4*)(h + idx);
    float4 sc = *(const float4*)(scale + col);
    float4 sh = *(const float4*)(shift + col);
    s4v o;
    o.x = f2bf(fmaxf(v.x * sc.x + sh.x, 0.f));
    o.y = f2bf(fmaxf(v.y * sc.y + sh.y, 0.f));
    o.z = f2bf(fmaxf(v.z * sc.z + sh.z, 0.f));
    o.w = f2bf(fmaxf(v.w * sc.w + sh.w, 0.f));
    *(s4v*)(hn + idx) = o;
}

// ---- 6. row L2 normalize + cast bf16 ----
__global__ __launch_bounds__(256) void rownorm(const float* __restrict__ z,
                                               short* __restrict__ zn) {
    __shared__ float red[4];
    int row = blockIdx.x, t = threadIdx.x;
    const float* zr = z + (long)row * DIM;
    float4 v0 = *(const float4*)(zr + t * 4);
    float4 v1 = *(const float4*)(zr + 1024 + t * 4);
    float ss = v0.x * v0.x + v0.y * v0.y + v0.z * v0.z + v0.w * v0.w
             + v1.x * v1.x + v1.y * v1.y + v1.z * v1.z + v1.w * v1.w;
#pragma unroll
    for (int m = 1; m < 64; m <<= 1) ss += __shfl_xor(ss, m);
    if ((t & 63) == 0) red[t >> 6] = ss;
    __syncthreads();
    float tot = red[0] + red[1] + red[2] + red[3];
    float inv = 1.0f / fmaxf(sqrtf(tot), 1e-8f);
    s4v a, b;
    a.x = f2bf(v0.x * inv); a.y = f2bf(v0.y * inv); a.z = f2bf(v0.z * inv); a.w = f2bf(v0.w * inv);
    b.x = f2bf(v1.x * inv); b.y = f2bf(v1.y * inv); b.z = f2bf(v1.z * inv); b.w = f2bf(v1.w * inv);
    *(s4v*)(zn + (long)row * DIM + t * 4) = a;
    *(s4v*)(zn + (long)row * DIM + 1024 + t * 4) = b;
}

// ---- 7. sum 4 split-K partials -> sim; also zero the 2-float output ----
__global__ __launch_bounds__(256) void ksum(const float* __restrict__ simp,
                                            float* __restrict__ sim,
                                            float* __restrict__ out) {
    int idx = (blockIdx.x * 256 + threadIdx.x) * 4;
    float4 a = *(const float4*)(simp + idx);
    float4 b = *(const float4*)(simp + 131072 + idx);
    float4 c = *(const float4*)(simp + 262144 + idx);
    float4 d = *(const float4*)(simp + 393216 + idx);
    float4 o;
    o.x = a.x + b.x + c.x + d.x;
    o.y = a.y + b.y + c.y + d.y;
    o.z = a.z + b.z + c.z + d.z;
    o.w = a.w + b.w + c.w + d.w;
    *(float4*)(sim + idx) = o;
    if (blockIdx.x == 0 && threadIdx.x == 0) { out[0] = 0.f; out[1] = 0.f; }
}

// ---- 8. loss: one row per wave, 64 blocks x 4 waves, atomicAdd finish ----
__global__ __launch_bounds__(256) void loss_kernel(const float* __restrict__ sim,
                                                   const int* __restrict__ rel,
                                                   float* __restrict__ out) {
    __shared__ float lsum[4];
    __shared__ float lcnt[4];
    int t = threadIdx.x, lane = t & 63, wave = t >> 6;
    int i = blockIdx.x * 4 + wave;   // row 0..255
    int reli = rel[i];
    float s[8];
    float neg = 0.f;
#pragma unroll
    for (int kk = 0; kk < 8; ++kk) {
        int j = lane + kk * 64;
        s[kk] = sim[i * 512 + j];
        float e = __expf(10.0f * s[kk]);
        if (j >= NB || abs(reli - rel[j]) > 2) neg += e;
    }
#pragma unroll
    for (int m = 1; m < 64; m <<= 1) neg += __shfl_xor(neg, m);
    float ts = 0.f; int cnt = 0;
#pragma unroll
    for (int kk = 0; kk < 4; ++kk) {
        int j = lane + kk * 64;
        if (j != i && abs(reli - rel[j]) <= 2) {
            ts += logf(__expf(10.0f * s[kk]) + neg) - 10.0f * s[kk];
            cnt++;
        }
    }
#pragma unroll
    for (int m = 1; m < 64; m <<= 1) {
        ts += __shfl_xor(ts, m);
        cnt += __shfl_xor(cnt, m);
    }
    if (lane == 0) {
        lsum[wave] = (cnt > 0) ? ts / (float)cnt : 0.f;
        lcnt[wave] = (cnt > 0) ? 1.f : 0.f;
    }
    __syncthreads();
    if (t == 0) {
        atomicAdd(&out[0], lsum[0] + lsum[1] + lsum[2] + lsum[3]);
        atomicAdd(&out[1], lcnt[0] + lcnt[1] + lcnt[2] + lcnt[3]);
    }
}

extern "C" void kernel_launch(void* const* d_in, const int* in_sizes, int n_in,
                              void* d_out, int out_size, void* d_ws, size_t ws_size,
                              hipStream_t stream) {
    const float* z0    = (const float*)d_in[0];
    const float* z1    = (const float*)d_in[1];
    const int*   rel0  = (const int*)d_in[2];
    const float* W1    = (const float*)d_in[4];
    const float* b1    = (const float*)d_in[5];
    const float* gamma = (const float*)d_in[6];
    const float* beta  = (const float*)d_in[7];
    const float* W2    = (const float*)d_in[8];
    const float* b2    = (const float*)d_in[9];

    char* ws = (char*)d_ws;
    short* p_bf  = (short*)(ws);                         // 2 MB
    short* W1b   = (short*)(ws + (2l  << 20));           // 8 MB
    short* W2b   = (short*)(ws + (10l << 20));           // 8 MB
    float* h     = (float*)(ws + (18l << 20));           // 4 MB (freed after bn_relu)
    float* scale = (float*)(ws + (22l << 20));           // 8 KB
    float* shift = (float*)(ws + (22l << 20) + 8192);    // 8 KB
    short* hn    = (short*)(ws + (23l << 20));           // 2 MB
    float* zproj = (float*)(ws + (25l << 20));           // 4 MB (freed after rownorm)
    short* zn    = (short*)(ws + (29l << 20));           // 2 MB
    float* simp  = (float*)(ws + (18l << 20));           // 2 MB, reuses h slot
    float* sim   = (float*)(ws + (25l << 20));           // 512 KB, reuses zproj slot

    pool_kernel<<<8192, 256, 0, stream>>>(z0, z1, p_bf);
    cast2_kernel<<<8192, 256, 0, stream>>>(W1, W2, W1b, W2b);
    gemm64<<<dim3(32, 8, 1), 256, 0, stream>>>(p_bf, W1b, b1, h, NROW, DIM, DIM, DIM);
    bn_stats<<<32, 256, 0, stream>>>(h, gamma, beta, scale, shift);
    bn_relu_cast<<<1024, 256, 0, stream>>>(h, scale, shift, hn);
    gemm64<<<dim3(32, 8, 1), 256, 0, stream>>>(hn, W2b, b2, zproj, NROW, DIM, DIM, DIM);
    rownorm<<<512, 256, 0, stream>>>(zproj, zn);
    gemm64<<<dim3(8, 4, 4), 256, 0, stream>>>(zn, zn, nullptr, simp, NB, NROW, DIM, 512);
    ksum<<<128, 256, 0, stream>>>(simp, sim, (float*)d_out);
    loss_kernel<<<64, 256, 0, stream>>>(sim, rel0, (float*)d_out);
}

// Round 3
// 372.344 us; speedup vs baseline: 1.3448x; 1.2740x over previous
//
#include <hip/hip_runtime.h>

typedef __attribute__((ext_vector_type(8))) short s8v;
typedef __attribute__((ext_vector_type(4))) short s4v;
typedef __attribute__((ext_vector_type(4))) float f4v;

#define DIM 2048
#define NROW 512   // 2*B
#define NB 256     // B

__device__ inline short f2bf(float f) {
    union { float f; unsigned int u; } v; v.f = f;
    unsigned int u = v.u;
    unsigned int r = (u + 0x7fffu + ((u >> 16) & 1u)) >> 16;
    return (short)r;
}

// pack two floats -> two truncated bf16 in one int (v_perm_b32).
// D.bytes = [a.b2, a.b3, b.b2, b.b3]  => low short = bf16(a), high short = bf16(b)
__device__ __forceinline__ int pk_trunc(float a, float b) {
    return __builtin_amdgcn_perm(__float_as_uint(b), __float_as_uint(a), 0x07060302);
}

// ---- 1. spatial mean pool, software-pipelined across 4 chunks/block ----
// chunk = 32 KB = 128 (row,dim) pairs. grid 2048, chunks c, c+2048, ...
__global__ __launch_bounds__(256) void pool_kernel(const float* __restrict__ z0,
                                                   const float* __restrict__ z1,
                                                   short* __restrict__ p) {
    int t = threadIdx.x;
    int c = blockIdx.x;
    float4 v[8], w[8];
    const float* src = (c < 4096) ? z0 + (long)c * 8192 : z1 + (long)(c - 4096) * 8192;
#pragma unroll
    for (int i = 0; i < 8; ++i) v[i] = *(const float4*)(src + i * 1024 + t * 4);
#pragma unroll
    for (int it = 0; it < 4; ++it) {
        int cn = c + 2048;
        if (it < 3) {
            const float* s2 = (cn < 4096) ? z0 + (long)cn * 8192 : z1 + (long)(cn - 4096) * 8192;
#pragma unroll
            for (int i = 0; i < 8; ++i) w[i] = *(const float4*)(s2 + i * 1024 + t * 4);
        }
        int pairBase = c * 128;
#pragma unroll
        for (int i = 0; i < 8; ++i) {
            float s = v[i].x + v[i].y + v[i].z + v[i].w;
            s += __shfl_xor(s, 1);
            s += __shfl_xor(s, 2);
            s += __shfl_xor(s, 4);
            s += __shfl_xor(s, 8);
            if ((t & 15) == 0) p[pairBase + i * 16 + (t >> 4)] = f2bf(s * (1.0f / 64.0f));
        }
        c = cn;
#pragma unroll
        for (int i = 0; i < 8; ++i) v[i] = w[i];
    }
}

// XOR-swizzled LDS address (shorts). stride 256, 16B-granule swizzle.
__device__ __forceinline__ int swz(int r, int k) { return r * 256 + (k ^ ((r & 7) << 3)); }

// ---- 2. bf16 NT GEMM: 64x64 tile, BK=256, 4 waves split K, LDS reduce ----
// C[z] [m][n] = sum_k A[m][k]*B[n][k] + bias[n].  B from bf16 (Bh) or fp32 (Bf,
// truncation-cast during staging).  Optional column sum/sumsq atomics (BN).
__global__ __launch_bounds__(256) void gemm_ks(const short* __restrict__ A,
                                               const short* __restrict__ Bh,
                                               const float* __restrict__ Bf,
                                               const float* __restrict__ bias,
                                               float* __restrict__ C,
                                               float* __restrict__ stats,
                                               int M, int N, int K, int kChunk) {
    __shared__ short sm[2 * 64 * 256];   // 64 KB; aliased as fp32 for reduce
    short* lA = sm;
    short* lB = sm + 64 * 256;
    int t = threadIdx.x;
    int n0 = blockIdx.x * 64, m0 = blockIdx.y * 64;
    int kbase = blockIdx.z * kChunk;
    long zoff = (long)blockIdx.z * M * N;
    int lane = t & 63, w = t >> 6;
    int l16 = lane & 15, quad = lane >> 4;
    int ks = w * 64;                     // this wave's K-slice inside BK
    f4v acc[4][4] = {};
    int sr = t >> 3;                     // 0..31 staging row
    int sq8 = (t & 7) * 8;               // 0..56 staging k-offset

    for (int it = 0; it < kChunk; it += 256) {
        int k0 = kbase + it;
#pragma unroll
        for (int pp = 0; pp < 2; ++pp) {
            int r = sr + pp * 32;
            const short* as = &A[(long)(m0 + r) * K + k0];
#pragma unroll
            for (int j = 0; j < 4; ++j)
                *(s8v*)&lA[swz(r, sq8 + j * 64)] = *(const s8v*)&as[sq8 + j * 64];
        }
        if (Bh) {
#pragma unroll
            for (int pp = 0; pp < 2; ++pp) {
                int r = sr + pp * 32;
                const short* bs = &Bh[(long)(n0 + r) * K + k0];
#pragma unroll
                for (int j = 0; j < 4; ++j)
                    *(s8v*)&lB[swz(r, sq8 + j * 64)] = *(const s8v*)&bs[sq8 + j * 64];
            }
        } else {
#pragma unroll
            for (int pp = 0; pp < 2; ++pp) {
                int r = sr + pp * 32;
                const float* bs = &Bf[(long)(n0 + r) * K + k0];
#pragma unroll
                for (int j = 0; j < 4; ++j) {
                    float4 x = *(const float4*)&bs[sq8 + j * 64];
                    float4 y = *(const float4*)&bs[sq8 + j * 64 + 4];
                    int4 o;
                    o.x = pk_trunc(x.x, x.y);
                    o.y = pk_trunc(x.z, x.w);
                    o.z = pk_trunc(y.x, y.y);
                    o.w = pk_trunc(y.z, y.w);
                    *(int4*)&lB[swz(r, sq8 + j * 64)] = o;
                }
            }
        }
        __syncthreads();
#pragma unroll
        for (int kk = 0; kk < 2; ++kk) {
            s8v af[4], bf[4];
#pragma unroll
            for (int i = 0; i < 4; ++i)
                af[i] = *(const s8v*)&lA[swz(i * 16 + l16, ks + kk * 32 + quad * 8)];
#pragma unroll
            for (int j = 0; j < 4; ++j)
                bf[j] = *(const s8v*)&lB[swz(j * 16 + l16, ks + kk * 32 + quad * 8)];
#pragma unroll
            for (int i = 0; i < 4; ++i)
#pragma unroll
                for (int j = 0; j < 4; ++j)
                    acc[i][j] = __builtin_amdgcn_mfma_f32_16x16x32_bf16(af[i], bf[j], acc[i][j], 0, 0, 0);
        }
        __syncthreads();
    }

    // cross-wave K reduction: each wave dumps 64x64 fp32 partial, then
    // thread t finalizes col c = t&63, rows (t>>6)*16 .. +16.
    float* fr = (float*)sm;
#pragma unroll
    for (int i = 0; i < 4; ++i)
#pragma unroll
        for (int j = 0; j < 4; ++j)
#pragma unroll
            for (int r = 0; r < 4; ++r)
                fr[w * 4096 + (i * 16 + quad * 4 + r) * 64 + j * 16 + l16] = acc[i][j][r];
    __syncthreads();
    int c = t & 63;
    int rbase = (t >> 6) * 16;
    float bv = bias ? bias[n0 + c] : 0.0f;
    float s = 0.f, q = 0.f;
#pragma unroll
    for (int r = 0; r < 16; ++r) {
        int rr = rbase + r;
        float h = fr[rr * 64 + c] + fr[4096 + rr * 64 + c]
                + fr[8192 + rr * 64 + c] + fr[12288 + rr * 64 + c] + bv;
        C[zoff + (long)(m0 + rr) * N + n0 + c] = h;
        s += h; q += h * h;
    }
    if (stats) {
        __syncthreads();
        fr[(t >> 6) * 64 + c] = s;
        fr[256 + (t >> 6) * 64 + c] = q;
        __syncthreads();
        if (t < 64) {
            float ss = fr[t] + fr[64 + t] + fr[128 + t] + fr[192 + t];
            float qq = fr[256 + t] + fr[320 + t] + fr[384 + t] + fr[448 + t];
            atomicAdd(&stats[n0 + t], ss);
            atomicAdd(&stats[2048 + n0 + t], qq);
        }
    }
}

// ---- 3. BN finalize: stats -> scale/shift ----
__global__ __launch_bounds__(256) void bn_finalize(const float* __restrict__ stats,
                                                   const float* __restrict__ gamma,
                                                   const float* __restrict__ beta,
                                                   float* __restrict__ scale,
                                                   float* __restrict__ shift) {
    int c = blockIdx.x * 256 + threadIdx.x;
    float mu = stats[c] * (1.0f / NROW);
    float var = stats[2048 + c] * (1.0f / NROW) - mu * mu;
    float sc = gamma[c] * rsqrtf(var + 1e-5f);
    scale[c] = sc;
    shift[c] = beta[c] - mu * sc;
}

// ---- 4. bn apply + relu + cast bf16 ----
__global__ __launch_bounds__(256) void bn_relu_cast(const float* __restrict__ h,
                                                    const float* __restrict__ scale,
                                                    const float* __restrict__ shift,
                                                    short* __restrict__ hn) {
    int idx = (blockIdx.x * 256 + threadIdx.x) * 4;
    int col = idx & (DIM - 1);
    float4 v = *(const float4*)(h + idx);
    float4 sc = *(const float4*)(scale + col);
    float4 sh = *(const float4*)(shift + col);
    s4v o;
    o.x = f2bf(fmaxf(v.x * sc.x + sh.x, 0.f));
    o.y = f2bf(fmaxf(v.y * sc.y + sh.y, 0.f));
    o.z = f2bf(fmaxf(v.z * sc.z + sh.z, 0.f));
    o.w = f2bf(fmaxf(v.w * sc.w + sh.w, 0.f));
    *(s4v*)(hn + idx) = o;
}

// ---- 5. row L2 normalize + cast bf16 ----
__global__ __launch_bounds__(256) void rownorm(const float* __restrict__ z,
                                               short* __restrict__ zn) {
    __shared__ float red[4];
    int row = blockIdx.x, t = threadIdx.x;
    const float* zr = z + (long)row * DIM;
    float4 v0 = *(const float4*)(zr + t * 4);
    float4 v1 = *(const float4*)(zr + 1024 + t * 4);
    float ss = v0.x * v0.x + v0.y * v0.y + v0.z * v0.z + v0.w * v0.w
             + v1.x * v1.x + v1.y * v1.y + v1.z * v1.z + v1.w * v1.w;
#pragma unroll
    for (int m = 1; m < 64; m <<= 1) ss += __shfl_xor(ss, m);
    if ((t & 63) == 0) red[t >> 6] = ss;
    __syncthreads();
    float tot = red[0] + red[1] + red[2] + red[3];
    float inv = 1.0f / fmaxf(sqrtf(tot), 1e-8f);
    s4v a, b;
    a.x = f2bf(v0.x * inv); a.y = f2bf(v0.y * inv); a.z = f2bf(v0.z * inv); a.w = f2bf(v0.w * inv);
    b.x = f2bf(v1.x * inv); b.y = f2bf(v1.y * inv); b.z = f2bf(v1.z * inv); b.w = f2bf(v1.w * inv);
    *(s4v*)(zn + (long)row * DIM + t * 4) = a;
    *(s4v*)(zn + (long)row * DIM + 1024 + t * 4) = b;
}

// ---- 6. sum 8 split-K partials -> sim; zero the 2-float output ----
__global__ __launch_bounds__(256) void ksum8(const float* __restrict__ simp,
                                             float* __restrict__ sim,
                                             float* __restrict__ out) {
    int idx = (blockIdx.x * 256 + threadIdx.x) * 4;
    float4 o = {0.f, 0.f, 0.f, 0.f};
#pragma unroll
    for (int z = 0; z < 8; ++z) {
        float4 a = *(const float4*)(simp + (long)z * 131072 + idx);
        o.x += a.x; o.y += a.y; o.z += a.z; o.w += a.w;
    }
    *(float4*)(sim + idx) = o;
    if (blockIdx.x == 0 && threadIdx.x == 0) { out[0] = 0.f; out[1] = 0.f; }
}

// ---- 7. loss: one row per wave, 64 blocks x 4 waves, atomicAdd finish ----
__global__ __launch_bounds__(256) void loss_kernel(const float* __restrict__ sim,
                                                   const int* __restrict__ rel,
                                                   float* __restrict__ out) {
    __shared__ float lsum[4];
    __shared__ float lcnt[4];
    int t = threadIdx.x, lane = t & 63, wave = t >> 6;
    int i = blockIdx.x * 4 + wave;
    int reli = rel[i];
    float s[8];
    float neg = 0.f;
#pragma unroll
    for (int kk = 0; kk < 8; ++kk) {
        int j = lane + kk * 64;
        s[kk] = sim[i * 512 + j];
        float e = __expf(10.0f * s[kk]);
        if (j >= NB || abs(reli - rel[j]) > 2) neg += e;
    }
#pragma unroll
    for (int m = 1; m < 64; m <<= 1) neg += __shfl_xor(neg, m);
    float ts = 0.f; int cnt = 0;
#pragma unroll
    for (int kk = 0; kk < 4; ++kk) {
        int j = lane + kk * 64;
        if (j != i && abs(reli - rel[j]) <= 2) {
            ts += logf(__expf(10.0f * s[kk]) + neg) - 10.0f * s[kk];
            cnt++;
        }
    }
#pragma unroll
    for (int m = 1; m < 64; m <<= 1) {
        ts += __shfl_xor(ts, m);
        cnt += __shfl_xor(cnt, m);
    }
    if (lane == 0) {
        lsum[wave] = (cnt > 0) ? ts / (float)cnt : 0.f;
        lcnt[wave] = (cnt > 0) ? 1.f : 0.f;
    }
    __syncthreads();
    if (t == 0) {
        atomicAdd(&out[0], lsum[0] + lsum[1] + lsum[2] + lsum[3]);
        atomicAdd(&out[1], lcnt[0] + lcnt[1] + lcnt[2] + lcnt[3]);
    }
}

extern "C" void kernel_launch(void* const* d_in, const int* in_sizes, int n_in,
                              void* d_out, int out_size, void* d_ws, size_t ws_size,
                              hipStream_t stream) {
    const float* z0    = (const float*)d_in[0];
    const float* z1    = (const float*)d_in[1];
    const int*   rel0  = (const int*)d_in[2];
    const float* W1    = (const float*)d_in[4];
    const float* b1    = (const float*)d_in[5];
    const float* gamma = (const float*)d_in[6];
    const float* beta  = (const float*)d_in[7];
    const float* W2    = (const float*)d_in[8];
    const float* b2    = (const float*)d_in[9];

    char* ws = (char*)d_ws;
    short* p_bf  = (short*)(ws);                         // 2 MB
    float* h     = (float*)(ws + (2l  << 20));           // 4 MB
    short* hn    = (short*)(ws + (6l  << 20));           // 2 MB
    float* zproj = (float*)(ws + (8l  << 20));           // 4 MB
    short* zn    = (short*)(ws + (12l << 20));           // 2 MB
    float* simp  = (float*)(ws + (14l << 20));           // 4 MB (8 x 512 KB)
    float* sim   = (float*)(ws + (18l << 20));           // 512 KB
    float* stats = (float*)(ws + (19l << 20));           // 16 KB (sum | sumsq)
    float* scale = (float*)(ws + (19l << 20) + 16384);   // 8 KB
    float* shift = (float*)(ws + (19l << 20) + 24576);   // 8 KB

    hipMemsetAsync(stats, 0, 16384, stream);
    pool_kernel<<<2048, 256, 0, stream>>>(z0, z1, p_bf);
    gemm_ks<<<dim3(32, 8, 1), 256, 0, stream>>>(p_bf, nullptr, W1, b1, h, stats,
                                                NROW, DIM, DIM, DIM);
    bn_finalize<<<8, 256, 0, stream>>>(stats, gamma, beta, scale, shift);
    bn_relu_cast<<<1024, 256, 0, stream>>>(h, scale, shift, hn);
    gemm_ks<<<dim3(32, 8, 1), 256, 0, stream>>>(hn, nullptr, W2, b2, zproj, nullptr,
                                                NROW, DIM, DIM, DIM);
    rownorm<<<512, 256, 0, stream>>>(zproj, zn);
    gemm_ks<<<dim3(8, 4, 8), 256, 0, stream>>>(zn, zn, nullptr, nullptr, simp, nullptr,
                                               NB, NROW, DIM, 256);
    ksum8<<<128, 256, 0, stream>>>(simp, sim, (float*)d_out);
    loss_kernel<<<64, 256, 0, stream>>>(sim, rel0, (float*)d_out);
}